// Round 2
// baseline (437.413 us; speedup 1.0000x reference)
//
#include <hip/hip_runtime.h>

// AvgSPP: x (16,256,256,64) f32 NHWC. SCALE=8 -> bin = (h>>5, w>>5) exactly
// (half-pixel-center NN formula degenerates to uniform 32x32 bins at 256/8),
// and s^2/(h*w) = 1/1024 = 1/bin_pixel_count -> out = per-bin mean broadcast.
// Fused one-pass: one block per (b,u,v) bin reads its 256 KB, reduces,
// broadcasts the 64 channel-means back over its own 32x32 output block.

__global__ __launch_bounds__(256) void spp_fused(const float4* __restrict__ x4,
                                                 float4* __restrict__ out4) {
    const int bin = blockIdx.x;          // [0, 16*8*8)
    const int v = bin & 7;               // bin col
    const int u = (bin >> 3) & 7;        // bin row
    const int b = bin >> 6;              // batch
    const int t = threadIdx.x;
    const int c4 = t & 15;               // float4 channel group (C=64 -> 16)
    const int rw = t >> 4;               // pixel phase [0,16)

    // float4 index of pixel (b, u*32, v*32), channel group c4
    const int base = ((b * 256 + u * 32) * 256 + v * 32) * 16 + c4;
    const float4* __restrict__ src = x4 + base;

    float4 acc = make_float4(0.f, 0.f, 0.f, 0.f);
    // pixel p = rw + 16*k covers the 1024 bin pixels exactly once; at fixed k
    // the block touches 16 consecutive pixels * 64 ch = 4 KB contiguous.
    #pragma unroll 8
    for (int k = 0; k < 64; ++k) {
        const int p = rw + (k << 4);
        const int r = p >> 5;            // row in bin [0,32)
        const int q = p & 31;            // col in bin [0,32)
        const float4 val = src[(r * 256 + q) * 16];
        acc.x += val.x; acc.y += val.y; acc.z += val.z; acc.w += val.w;
    }

    __shared__ float4 red[256];
    red[t] = acc;
    __syncthreads();
    // tree-reduce over the 16 pixel-phases (worst LDS aliasing is 2-way: free)
    for (int s = 8; s >= 1; s >>= 1) {
        if (rw < s) {
            const float4 o = red[(rw + s) * 16 + c4];
            float4 m = red[t];
            m.x += o.x; m.y += o.y; m.z += o.z; m.w += o.w;
            red[t] = m;
        }
        __syncthreads();
    }

    // every thread grabs its channel-group's mean (lanes 16.. broadcast-read)
    float4 m = red[c4];
    const float inv = 1.0f / 1024.0f;    // = s*s/(h*w) = 1/bin_pixel_count
    m.x *= inv; m.y *= inv; m.z *= inv; m.w *= inv;

    float4* __restrict__ dst = out4 + base;
    #pragma unroll 8
    for (int k = 0; k < 64; ++k) {
        const int p = rw + (k << 4);
        const int r = p >> 5;
        const int q = p & 31;
        dst[(r * 256 + q) * 16] = m;
    }
}

extern "C" void kernel_launch(void* const* d_in, const int* in_sizes, int n_in,
                              void* d_out, int out_size, void* d_ws, size_t ws_size,
                              hipStream_t stream) {
    const float4* x4   = (const float4*)d_in[0];
    float4*       out4 = (float4*)d_out;
    spp_fused<<<dim3(16 * 8 * 8), dim3(256), 0, stream>>>(x4, out4);
}